// Round 3
// baseline (44.840 us; speedup 1.0000x reference)
//
#include <hip/hip_runtime.h>
#include <math.h>

#define N_RAYS 65536
#define N_SAMPLES 256
#define T_THRESHOLD 1e-4f
#define NEAR_DISTANCE 0.01f

// d_ws layout:
//   [0, 4)                     : unsigned int counter (zeroed via memset each call)
//   [16, 16 + 4*N_RAYS)        : int   list[N_RAYS]   (compacted hit-ray indices)
//   [16 + 4*N_RAYS, +4*N_RAYS) : float deltas[N_RAYS]
#define WS_LIST_OFF   16
#define WS_DELTA_OFF  (16 + 4 * N_RAYS)
#define WS_NEEDED     (16 + 8 * N_RAYS)

__device__ __forceinline__ void ray_aabb(
    const float* __restrict__ rp,
    const float* __restrict__ center,
    const float* __restrict__ half_size,
    bool& hit, float& delta)
{
    float o[3] = { rp[0], rp[1], rp[2] };
    float d[3] = { rp[3], rp[4], rp[5] };
    float inv_norm = 1.0f / (sqrtf(d[0]*d[0] + d[1]*d[1] + d[2]*d[2]) + 1e-8f);
    d[0] *= inv_norm; d[1] *= inv_norm; d[2] *= inv_norm;

    float tmin = -INFINITY, tmax = INFINITY;
    #pragma unroll
    for (int a = 0; a < 3; ++a) {
        float da  = (fabsf(d[a]) > 1e-8f) ? d[a] : 1e-8f;
        float inv = 1.0f / da;
        float t1  = (center[a] - half_size[a] - o[a]) * inv;
        float t2  = (center[a] + half_size[a] - o[a]) * inv;
        tmin = fmaxf(tmin, fminf(t1, t2));
        tmax = fminf(tmax, fmaxf(t1, t2));
    }
    hit = tmax > fmaxf(tmin, 0.0f);
    float near = fmaxf(tmin, 0.0f);
    if (hit && near < NEAR_DISTANCE) near = NEAR_DISTANCE;
    const float far = hit ? tmax : near;
    delta = (far - near) * (1.0f / (float)N_SAMPLES);
}

// Pass 1: one thread per ray. Reads only `rays` (1.5 MB). Misses write
// zero output; hits append their index to the compact list.
__global__ __launch_bounds__(256) void ngp_setup_kernel(
    const float* __restrict__ rays,
    const float* __restrict__ center,
    const float* __restrict__ half_size,
    float* __restrict__ out,
    unsigned int* __restrict__ counter,
    int* __restrict__ list,
    float* __restrict__ deltas)
{
    const int ray = blockIdx.x * blockDim.x + threadIdx.x;
    if (ray >= N_RAYS) return;

    bool hit; float delta;
    ray_aabb(rays + (size_t)ray * 6, center, half_size, hit, delta);

    if (!hit) {
        float* op = out + (size_t)ray * 3;
        op[0] = 0.0f; op[1] = 0.0f; op[2] = 0.0f;
    } else {
        deltas[ray] = delta;
        const unsigned int pos = atomicAdd(counter, 1u);
        list[pos] = ray;
    }
}

// Pass 2: persistent waves. One 64-lane wave renders one compacted ray per
// iteration; lane l handles samples [4l, 4l+4).
__global__ __launch_bounds__(256) void ngp_render_kernel(
    const float* __restrict__ sigmas,    // [N_RAYS, N_SAMPLES]
    const float* __restrict__ rgbs,      // [N_RAYS, N_SAMPLES, 3]
    float* __restrict__ out,             // [N_RAYS, 3]
    const unsigned int* __restrict__ counter,
    const int* __restrict__ list,
    const float* __restrict__ deltas)
{
    const int lane    = threadIdx.x & 63;
    const int waveId  = (blockIdx.x * blockDim.x + threadIdx.x) >> 6;
    const int nWaves  = (gridDim.x * blockDim.x) >> 6;
    const unsigned int count = *counter;

    for (unsigned int w = waveId; w < count; w += nWaves) {
        const int   ray   = list[w];
        const float delta = deltas[ray];

        // ---- sigma * delta, local prefix over 4 samples ----
        const float4 sg = *reinterpret_cast<const float4*>(
            sigmas + (size_t)ray * N_SAMPLES + lane * 4);
        const float sd0 = sg.x * delta;
        const float sd1 = sg.y * delta;
        const float sd2 = sg.z * delta;
        const float sd3 = sg.w * delta;
        const float p0 = sd0;
        const float p1 = p0 + sd1;
        const float p2 = p1 + sd2;
        const float p3 = p2 + sd3;        // lane total

        // ---- wave-inclusive scan of lane totals ----
        float incl = p3;
        #pragma unroll
        for (int off = 1; off < 64; off <<= 1) {
            float v = __shfl_up(incl, off, 64);
            if (lane >= off) incl += v;
        }
        const float excl = incl - p3;

        // ---- transmittance, alpha, weights ----
        const float T0 = expf(-excl);
        const float T1 = expf(-(excl + p0));
        const float T2 = expf(-(excl + p1));
        const float T3 = expf(-(excl + p2));
        const float a0 = 1.0f - expf(-sd0);
        const float a1 = 1.0f - expf(-sd1);
        const float a2 = 1.0f - expf(-sd2);
        const float a3 = 1.0f - expf(-sd3);
        const float ws0 = (T0 >= T_THRESHOLD) ? a0 * T0 : 0.0f;
        const float ws1 = (T1 >= T_THRESHOLD) ? a1 * T1 : 0.0f;
        const float ws2 = (T2 >= T_THRESHOLD) ? a2 * T2 : 0.0f;
        const float ws3 = (T3 >= T_THRESHOLD) ? a3 * T3 : 0.0f;

        // ---- rgbs: 48 contiguous bytes per lane ----
        const float* rb = rgbs + (size_t)ray * N_SAMPLES * 3 + (size_t)lane * 12;
        const float4 r0 = *reinterpret_cast<const float4*>(rb + 0);
        const float4 r1 = *reinterpret_cast<const float4*>(rb + 4);
        const float4 r2 = *reinterpret_cast<const float4*>(rb + 8);
        float R = ws0 * r0.x + ws1 * r0.w + ws2 * r1.z + ws3 * r2.y;
        float G = ws0 * r0.y + ws1 * r1.x + ws2 * r1.w + ws3 * r2.z;
        float B = ws0 * r0.z + ws1 * r1.y + ws2 * r2.x + ws3 * r2.w;

        // ---- wave reduce ----
        #pragma unroll
        for (int off = 32; off > 0; off >>= 1) {
            R += __shfl_xor(R, off, 64);
            G += __shfl_xor(G, off, 64);
            B += __shfl_xor(B, off, 64);
        }
        if (lane == 0) {
            float* op = out + (size_t)ray * 3;
            op[0] = R; op[1] = G; op[2] = B;
        }
    }
}

// Fallback single-pass kernel (used only if ws_size is too small).
__global__ __launch_bounds__(256) void ngp_onepass_kernel(
    const float* __restrict__ rays,
    const float* __restrict__ sigmas,
    const float* __restrict__ rgbs,
    const float* __restrict__ center,
    const float* __restrict__ half_size,
    float* __restrict__ out)
{
    const int gtid = blockIdx.x * blockDim.x + threadIdx.x;
    const int ray  = gtid >> 6;
    const int lane = threadIdx.x & 63;
    if (ray >= N_RAYS) return;

    bool hit; float delta;
    ray_aabb(rays + (size_t)ray * 6, center, half_size, hit, delta);

    if (!hit) {
        if (lane == 0) {
            float* op = out + (size_t)ray * 3;
            op[0] = 0.0f; op[1] = 0.0f; op[2] = 0.0f;
        }
        return;
    }

    const float4 sg = *reinterpret_cast<const float4*>(
        sigmas + (size_t)ray * N_SAMPLES + lane * 4);
    const float sd0 = sg.x * delta, sd1 = sg.y * delta;
    const float sd2 = sg.z * delta, sd3 = sg.w * delta;
    const float p0 = sd0, p1 = p0 + sd1, p2 = p1 + sd2, p3 = p2 + sd3;

    float incl = p3;
    #pragma unroll
    for (int off = 1; off < 64; off <<= 1) {
        float v = __shfl_up(incl, off, 64);
        if (lane >= off) incl += v;
    }
    const float excl = incl - p3;

    const float T0 = expf(-excl);
    const float T1 = expf(-(excl + p0));
    const float T2 = expf(-(excl + p1));
    const float T3 = expf(-(excl + p2));
    const float a0 = 1.0f - expf(-sd0), a1 = 1.0f - expf(-sd1);
    const float a2 = 1.0f - expf(-sd2), a3 = 1.0f - expf(-sd3);
    const float ws0 = (T0 >= T_THRESHOLD) ? a0 * T0 : 0.0f;
    const float ws1 = (T1 >= T_THRESHOLD) ? a1 * T1 : 0.0f;
    const float ws2 = (T2 >= T_THRESHOLD) ? a2 * T2 : 0.0f;
    const float ws3 = (T3 >= T_THRESHOLD) ? a3 * T3 : 0.0f;

    const float* rb = rgbs + (size_t)ray * N_SAMPLES * 3 + (size_t)lane * 12;
    const float4 r0 = *reinterpret_cast<const float4*>(rb + 0);
    const float4 r1 = *reinterpret_cast<const float4*>(rb + 4);
    const float4 r2 = *reinterpret_cast<const float4*>(rb + 8);
    float R = ws0 * r0.x + ws1 * r0.w + ws2 * r1.z + ws3 * r2.y;
    float G = ws0 * r0.y + ws1 * r1.x + ws2 * r1.w + ws3 * r2.z;
    float B = ws0 * r0.z + ws1 * r1.y + ws2 * r2.x + ws3 * r2.w;

    #pragma unroll
    for (int off = 32; off > 0; off >>= 1) {
        R += __shfl_xor(R, off, 64);
        G += __shfl_xor(G, off, 64);
        B += __shfl_xor(B, off, 64);
    }
    if (lane == 0) {
        float* op = out + (size_t)ray * 3;
        op[0] = R; op[1] = G; op[2] = B;
    }
}

extern "C" void kernel_launch(void* const* d_in, const int* in_sizes, int n_in,
                              void* d_out, int out_size, void* d_ws, size_t ws_size,
                              hipStream_t stream) {
    const float* rays      = (const float*)d_in[0];
    const float* sigmas    = (const float*)d_in[1];
    const float* rgbs      = (const float*)d_in[2];
    const float* center    = (const float*)d_in[3];
    const float* half_size = (const float*)d_in[4];
    float* out = (float*)d_out;

    if (ws_size >= (size_t)WS_NEEDED) {
        unsigned int* counter = (unsigned int*)d_ws;
        int*   list   = (int*)  ((char*)d_ws + WS_LIST_OFF);
        float* deltas = (float*)((char*)d_ws + WS_DELTA_OFF);

        hipMemsetAsync(counter, 0, 4, stream);

        ngp_setup_kernel<<<N_RAYS / 256, 256, 0, stream>>>(
            rays, center, half_size, out, counter, list, deltas);

        // Persistent waves: 256 CU * 32 waves = 8192 waves = 2048 blocks of 256.
        ngp_render_kernel<<<2048, 256, 0, stream>>>(
            sigmas, rgbs, out, counter, list, deltas);
    } else {
        ngp_onepass_kernel<<<N_RAYS / 4, 256, 0, stream>>>(
            rays, sigmas, rgbs, center, half_size, out);
    }
}

// Round 4
// 30.372 us; speedup vs baseline: 1.4763x; 1.4763x over previous
//
#include <hip/hip_runtime.h>
#include <math.h>

#define N_RAYS 65536
#define N_SAMPLES 256
#define T_THRESHOLD 1e-4f
#define NEAR_DISTANCE 0.01f
#define RAYS_PER_WAVE 8   // lanes 0..7 do setup; wave renders hits in order
#define WAVES_PER_BLOCK 4

// One wave handles 8 consecutive rays: computes hit/delta 8-wide, then
// renders only the hit rays (in ray order -> preserves streaming locality),
// software-pipelining the next ray's sigma/rgb loads under the current
// ray's scan/exp/reduce.
__global__ __launch_bounds__(256) void ngp_render_kernel(
    const float* __restrict__ rays,      // [N_RAYS, 6]
    const float* __restrict__ sigmas,    // [N_RAYS, N_SAMPLES]
    const float* __restrict__ rgbs,      // [N_RAYS, N_SAMPLES, 3]
    const float* __restrict__ center,    // [3]
    const float* __restrict__ half_size, // [3]
    float* __restrict__ out)             // [N_RAYS, 3]
{
    const int lane   = threadIdx.x & 63;
    const int waveId = (blockIdx.x * blockDim.x + threadIdx.x) >> 6;
    const int base   = waveId * RAYS_PER_WAVE;
    if (base >= N_RAYS) return;

    // ---- setup: lanes 0..7 each compute AABB for one ray ----
    bool  hit   = false;
    float delta = 0.0f;
    if (lane < RAYS_PER_WAVE) {
        const float* rp = rays + (size_t)(base + lane) * 6;
        float o[3] = { rp[0], rp[1], rp[2] };
        float d[3] = { rp[3], rp[4], rp[5] };
        float inv_norm = 1.0f / (sqrtf(d[0]*d[0] + d[1]*d[1] + d[2]*d[2]) + 1e-8f);
        d[0] *= inv_norm; d[1] *= inv_norm; d[2] *= inv_norm;

        float tmin = -INFINITY, tmax = INFINITY;
        #pragma unroll
        for (int a = 0; a < 3; ++a) {
            float da  = (fabsf(d[a]) > 1e-8f) ? d[a] : 1e-8f;
            float inv = 1.0f / da;
            float t1  = (center[a] - half_size[a] - o[a]) * inv;
            float t2  = (center[a] + half_size[a] - o[a]) * inv;
            tmin = fmaxf(tmin, fminf(t1, t2));
            tmax = fminf(tmax, fmaxf(t1, t2));
        }
        hit = tmax > fmaxf(tmin, 0.0f);
        if (hit) {
            float near = fmaxf(tmin, 0.0f);
            if (near < NEAR_DISTANCE) near = NEAR_DISTANCE;
            delta = (tmax - near) * (1.0f / (float)N_SAMPLES);
        } else {
            // miss: output is exactly zero
            float* op = out + (size_t)(base + lane) * 3;
            op[0] = 0.0f; op[1] = 0.0f; op[2] = 0.0f;
        }
    }

    unsigned long long m = __ballot(hit);   // wave-uniform hit mask (bits 0..7)
    if (m == 0ull) return;

    // ---- pipelined render loop over hit rays, in ray order ----
    // prologue: load first hit ray's data
    int src = __ffsll((unsigned long long)m) - 1;
    m &= m - 1;
    int   ray_n = base + src;
    float dlt_n = __shfl(delta, src, 64);
    const float* sp = sigmas + (size_t)ray_n * N_SAMPLES + lane * 4;
    const float* rb = rgbs   + (size_t)ray_n * N_SAMPLES * 3 + (size_t)lane * 12;
    float4 sg_n = *reinterpret_cast<const float4*>(sp);
    float4 r0_n = *reinterpret_cast<const float4*>(rb + 0);
    float4 r1_n = *reinterpret_cast<const float4*>(rb + 4);
    float4 r2_n = *reinterpret_cast<const float4*>(rb + 8);

    bool more = true;
    while (more) {
        // shift pipeline: current <- next
        const int    ray_c = ray_n;
        const float  dlt_c = dlt_n;
        const float4 sg = sg_n, r0 = r0_n, r1 = r1_n, r2 = r2_n;

        // issue next ray's loads (hidden under current ray's compute)
        more = (m != 0ull);
        if (more) {
            src = __ffsll((unsigned long long)m) - 1;
            m &= m - 1;
            ray_n = base + src;
            dlt_n = __shfl(delta, src, 64);
            const float* spn = sigmas + (size_t)ray_n * N_SAMPLES + lane * 4;
            const float* rbn = rgbs   + (size_t)ray_n * N_SAMPLES * 3 + (size_t)lane * 12;
            sg_n = *reinterpret_cast<const float4*>(spn);
            r0_n = *reinterpret_cast<const float4*>(rbn + 0);
            r1_n = *reinterpret_cast<const float4*>(rbn + 4);
            r2_n = *reinterpret_cast<const float4*>(rbn + 8);
        }

        // ---- compute current ray ----
        const float sd0 = sg.x * dlt_c;
        const float sd1 = sg.y * dlt_c;
        const float sd2 = sg.z * dlt_c;
        const float sd3 = sg.w * dlt_c;
        const float p0 = sd0;
        const float p1 = p0 + sd1;
        const float p2 = p1 + sd2;
        const float p3 = p2 + sd3;        // lane total

        // wave-inclusive scan of lane totals
        float incl = p3;
        #pragma unroll
        for (int off = 1; off < 64; off <<= 1) {
            float v = __shfl_up(incl, off, 64);
            if (lane >= off) incl += v;
        }
        const float excl = incl - p3;

        const float T0 = expf(-excl);
        const float T1 = expf(-(excl + p0));
        const float T2 = expf(-(excl + p1));
        const float T3 = expf(-(excl + p2));
        const float a0 = 1.0f - expf(-sd0);
        const float a1 = 1.0f - expf(-sd1);
        const float a2 = 1.0f - expf(-sd2);
        const float a3 = 1.0f - expf(-sd3);
        const float ws0 = (T0 >= T_THRESHOLD) ? a0 * T0 : 0.0f;
        const float ws1 = (T1 >= T_THRESHOLD) ? a1 * T1 : 0.0f;
        const float ws2 = (T2 >= T_THRESHOLD) ? a2 * T2 : 0.0f;
        const float ws3 = (T3 >= T_THRESHOLD) ? a3 * T3 : 0.0f;

        // sample 4l+0 -> (r0.x,r0.y,r0.z)   4l+1 -> (r0.w,r1.x,r1.y)
        // sample 4l+2 -> (r1.z,r1.w,r2.x)   4l+3 -> (r2.y,r2.z,r2.w)
        float R = ws0 * r0.x + ws1 * r0.w + ws2 * r1.z + ws3 * r2.y;
        float G = ws0 * r0.y + ws1 * r1.x + ws2 * r1.w + ws3 * r2.z;
        float B = ws0 * r0.z + ws1 * r1.y + ws2 * r2.x + ws3 * r2.w;

        #pragma unroll
        for (int off = 32; off > 0; off >>= 1) {
            R += __shfl_xor(R, off, 64);
            G += __shfl_xor(G, off, 64);
            B += __shfl_xor(B, off, 64);
        }
        if (lane == 0) {
            float* op = out + (size_t)ray_c * 3;
            op[0] = R; op[1] = G; op[2] = B;
        }
    }
}

extern "C" void kernel_launch(void* const* d_in, const int* in_sizes, int n_in,
                              void* d_out, int out_size, void* d_ws, size_t ws_size,
                              hipStream_t stream) {
    const float* rays      = (const float*)d_in[0];
    const float* sigmas    = (const float*)d_in[1];
    const float* rgbs      = (const float*)d_in[2];
    const float* center    = (const float*)d_in[3];
    const float* half_size = (const float*)d_in[4];
    float* out = (float*)d_out;

    const int raysPerBlock = RAYS_PER_WAVE * WAVES_PER_BLOCK;   // 32
    const int blocks = N_RAYS / raysPerBlock;                   // 2048
    ngp_render_kernel<<<blocks, 256, 0, stream>>>(
        rays, sigmas, rgbs, center, half_size, out);
}

// Round 5
// 24.905 us; speedup vs baseline: 1.8005x; 1.2195x over previous
//
#include <hip/hip_runtime.h>
#include <math.h>

#define N_RAYS 65536
#define N_SAMPLES 256
#define T_THRESHOLD 1e-4f
#define NEAR_DISTANCE 0.01f

// ---- DPP helpers: cross-lane adds on the VALU pipe (no LDS traffic) ----
// update_dpp(old=0, src, ctrl, row_mask, bank_mask=0xf, bound_ctrl=false):
// invalid source lanes contribute 0 (identity).
template <int CTRL, int ROW_MASK>
__device__ __forceinline__ float dpp_add(float v) {
    int iv = __builtin_bit_cast(int, v);
    int sh = __builtin_amdgcn_update_dpp(0, iv, CTRL, ROW_MASK, 0xf, false);
    return v + __builtin_bit_cast(float, sh);
}

// Wave64 inclusive scan (LLVM AMDGPUAtomicOptimizer sequence).
// After this, lane i holds sum of lanes [0..i]; lane 63 holds the total.
__device__ __forceinline__ float wave_incl_scan(float x) {
    x = dpp_add<0x111, 0xf>(x);   // row_shr:1
    x = dpp_add<0x112, 0xf>(x);   // row_shr:2
    x = dpp_add<0x114, 0xf>(x);   // row_shr:4
    x = dpp_add<0x118, 0xf>(x);   // row_shr:8
    x = dpp_add<0x142, 0xa>(x);   // row_bcast:15 -> rows 1,3
    x = dpp_add<0x143, 0xc>(x);   // row_bcast:31 -> rows 2,3
    return x;
}

// One 64-lane wave per ray. Lane l handles samples [4l, 4l+4).
// Miss rays exit after writing zeros (wave-uniform; skips sigma/rgb bytes).
__global__ __launch_bounds__(256) void ngp_render_kernel(
    const float* __restrict__ rays,      // [N_RAYS, 6]
    const float* __restrict__ sigmas,    // [N_RAYS, N_SAMPLES]
    const float* __restrict__ rgbs,      // [N_RAYS, N_SAMPLES, 3]
    const float* __restrict__ center,    // [3]
    const float* __restrict__ half_size, // [3]
    float* __restrict__ out)             // [N_RAYS, 3]
{
    const int gtid = blockIdx.x * blockDim.x + threadIdx.x;
    const int ray  = gtid >> 6;          // wave index == ray index
    const int lane = threadIdx.x & 63;
    if (ray >= N_RAYS) return;

    // ---- ray setup: every lane computes the same (broadcast loads) ----
    const float* rp = rays + (size_t)ray * 6;
    float o[3] = { rp[0], rp[1], rp[2] };
    float d[3] = { rp[3], rp[4], rp[5] };
    float inv_norm = 1.0f / (sqrtf(d[0]*d[0] + d[1]*d[1] + d[2]*d[2]) + 1e-8f);
    d[0] *= inv_norm; d[1] *= inv_norm; d[2] *= inv_norm;

    float tmin = -INFINITY, tmax = INFINITY;
    #pragma unroll
    for (int a = 0; a < 3; ++a) {
        float da  = (fabsf(d[a]) > 1e-8f) ? d[a] : 1e-8f;
        float inv = 1.0f / da;
        float t1  = (center[a] - half_size[a] - o[a]) * inv;
        float t2  = (center[a] + half_size[a] - o[a]) * inv;
        tmin = fmaxf(tmin, fminf(t1, t2));
        tmax = fminf(tmax, fmaxf(t1, t2));
    }
    const bool hit = tmax > fmaxf(tmin, 0.0f);

    if (!hit) {
        if (lane == 0) {
            float* op = out + (size_t)ray * 3;
            op[0] = 0.0f; op[1] = 0.0f; op[2] = 0.0f;
        }
        return;
    }

    float near = fmaxf(tmin, 0.0f);
    if (near < NEAR_DISTANCE) near = NEAR_DISTANCE;
    const float delta = (tmax - near) * (1.0f / (float)N_SAMPLES);

    // ---- sigma * delta, local prefix over 4 samples ----
    const float4 sg = *reinterpret_cast<const float4*>(
        sigmas + (size_t)ray * N_SAMPLES + lane * 4);
    const float sd0 = sg.x * delta;
    const float sd1 = sg.y * delta;
    const float sd2 = sg.z * delta;
    const float sd3 = sg.w * delta;
    const float p0 = sd0;
    const float p1 = p0 + sd1;
    const float p2 = p1 + sd2;
    const float p3 = p2 + sd3;        // lane total

    // ---- wave-inclusive scan of lane totals (DPP, VALU-only) ----
    const float incl = wave_incl_scan(p3);
    const float excl = incl - p3;     // exclusive prefix entering this lane

    // ---- transmittance, alpha, weights ----
    const float T0 = __expf(-excl);
    const float T1 = __expf(-(excl + p0));
    const float T2 = __expf(-(excl + p1));
    const float T3 = __expf(-(excl + p2));
    const float a0 = 1.0f - __expf(-sd0);
    const float a1 = 1.0f - __expf(-sd1);
    const float a2 = 1.0f - __expf(-sd2);
    const float a3 = 1.0f - __expf(-sd3);
    const float ws0 = (T0 >= T_THRESHOLD) ? a0 * T0 : 0.0f;
    const float ws1 = (T1 >= T_THRESHOLD) ? a1 * T1 : 0.0f;
    const float ws2 = (T2 >= T_THRESHOLD) ? a2 * T2 : 0.0f;
    const float ws3 = (T3 >= T_THRESHOLD) ? a3 * T3 : 0.0f;

    // ---- rgbs: 48 contiguous bytes per lane, 3 aligned float4 loads ----
    const float* rb = rgbs + (size_t)ray * N_SAMPLES * 3 + (size_t)lane * 12;
    const float4 r0 = *reinterpret_cast<const float4*>(rb + 0);
    const float4 r1 = *reinterpret_cast<const float4*>(rb + 4);
    const float4 r2 = *reinterpret_cast<const float4*>(rb + 8);
    // sample 4l+0 -> (r0.x,r0.y,r0.z)   4l+1 -> (r0.w,r1.x,r1.y)
    // sample 4l+2 -> (r1.z,r1.w,r2.x)   4l+3 -> (r2.y,r2.z,r2.w)
    float R = ws0 * r0.x + ws1 * r0.w + ws2 * r1.z + ws3 * r2.y;
    float G = ws0 * r0.y + ws1 * r1.x + ws2 * r1.w + ws3 * r2.z;
    float B = ws0 * r0.z + ws1 * r1.y + ws2 * r2.x + ws3 * r2.w;

    // ---- wave reduce via DPP scan (total lands in lane 63) ----
    R = wave_incl_scan(R);
    G = wave_incl_scan(G);
    B = wave_incl_scan(B);
    if (lane == 63) {
        float* op = out + (size_t)ray * 3;
        op[0] = R; op[1] = G; op[2] = B;
    }
}

extern "C" void kernel_launch(void* const* d_in, const int* in_sizes, int n_in,
                              void* d_out, int out_size, void* d_ws, size_t ws_size,
                              hipStream_t stream) {
    const float* rays      = (const float*)d_in[0];
    const float* sigmas    = (const float*)d_in[1];
    const float* rgbs      = (const float*)d_in[2];
    const float* center    = (const float*)d_in[3];
    const float* half_size = (const float*)d_in[4];
    float* out = (float*)d_out;

    const int threads = 256;                     // 4 waves -> 4 rays per block
    const int blocks  = N_RAYS / 4;              // 16384
    ngp_render_kernel<<<blocks, threads, 0, stream>>>(
        rays, sigmas, rgbs, center, half_size, out);
}